// Round 7
// baseline (276.955 us; speedup 1.0000x reference)
//
#include <hip/hip_runtime.h>
#include <hip/hip_bf16.h>

// Problem constants
#define B_   2
#define N_   512
#define M_   512
#define D_   128    // Dq = Dk = Dv
#define DE_  64
#define H_   8
#define O_   32
#define OUT_ 128
#define DKE_ 192    // Dk + De
#define MP_  516    // padded M for attn_s rows

typedef unsigned short u16;
typedef unsigned int   u32;
typedef short bf16x8 __attribute__((ext_vector_type(8)));
typedef float floatx4 __attribute__((ext_vector_type(4)));
typedef u32   u32x4  __attribute__((ext_vector_type(4)));

__device__ __forceinline__ u32 pk2bf(float a, float b) {
    __hip_bfloat162 h = __float22bfloat162_rn(make_float2(a, b));
    return *reinterpret_cast<u32*>(&h);
}
__device__ __forceinline__ u16 f2bf(float a) {
    __hip_bfloat16 h = __float2bfloat16(a);
    return *reinterpret_cast<u16*>(&h);
}
__device__ __forceinline__ float bf2f(u16 x) {
    return __uint_as_float(((u32)x) << 16);
}
__device__ __forceinline__ bf16x8 pack8(const float4 a, const float4 b) {
    u32x4 w;
    w.x = pk2bf(a.x, a.y); w.y = pk2bf(a.z, a.w);
    w.z = pk2bf(b.x, b.y); w.w = pk2bf(b.z, b.w);
    return __builtin_bit_cast(bf16x8, w);
}
// async global->LDS DMA, 16 B per lane; LDS dst = wave-uniform base + lane*16
__device__ __forceinline__ void dma16(const float* g, void* l) {
    __builtin_amdgcn_global_load_lds(
        (const __attribute__((address_space(1))) float*)g,
        (__attribute__((address_space(3))) float*)l, 16, 0, 0);
}
#define MEMFENCE() __asm__ volatile("" ::: "memory")

// ---------------------------------------------------------------------------
// k_proj, grid = 272 x 256:
//  blocks 0..127  : qE bf16 [b*N+n][h*192+j]   (q = query@Wq/sqrt(32), then @Wk)
//  blocks 128..255: vvT bf16 [b][col=h*32+o][m] (value @ Wv, transposed)
//  blocks 256..271: keyB bf16 [b][m][0..127]    (dtype cast of key)
// ---------------------------------------------------------------------------
__global__ __launch_bounds__(256) void k_proj(
    const float* __restrict__ query, const float* __restrict__ Wq,
    const float* __restrict__ Wk,
    const float* __restrict__ value, const float* __restrict__ Wv,
    const float* __restrict__ key,
    u16* __restrict__ qE, u16* __restrict__ vvT, u16* __restrict__ keyB)
{
    const int t = threadIdx.x;
    __shared__ float Xs[8][D_];
    __shared__ float qh[8][H_ * O_];

    if (blockIdx.x < 128) {
        const int r0 = blockIdx.x * 8;
        reinterpret_cast<float4*>(&Xs[0][0])[t] =
            reinterpret_cast<const float4*>(query + (size_t)r0 * D_)[t];
        __syncthreads();
        {
            float acc[8] = {0,0,0,0,0,0,0,0};
            const float* wcol = Wq + (t >> 5) * (D_ * O_) + (t & 31);
            for (int k = 0; k < D_; k += 4) {
                const float w0 = wcol[(k+0) * O_];
                const float w1 = wcol[(k+1) * O_];
                const float w2 = wcol[(k+2) * O_];
                const float w3 = wcol[(k+3) * O_];
#pragma unroll
                for (int r = 0; r < 8; ++r) {
                    const float4 x = *reinterpret_cast<const float4*>(&Xs[r][k]);
                    acc[r] += x.x * w0 + x.y * w1 + x.z * w2 + x.w * w3;
                }
            }
#pragma unroll
            for (int r = 0; r < 8; ++r) qh[r][t] = acc[r] * 0.17677669529663687f;
        }
        __syncthreads();

        for (int s = 0; s < 6; ++s) {
            const int hj = t + 256 * s;
            const int h  = hj / DKE_;
            float w[O_];
#pragma unroll
            for (int i = 0; i < O_ / 4; ++i) {
                const float4 x = reinterpret_cast<const float4*>(Wk + (size_t)hj * O_)[i];
                w[4*i] = x.x; w[4*i+1] = x.y; w[4*i+2] = x.z; w[4*i+3] = x.w;
            }
#pragma unroll
            for (int r = 0; r < 8; ++r) {
                const float* qrow = &qh[r][h * O_];
                float a = 0.f;
#pragma unroll
                for (int i = 0; i < O_ / 4; ++i) {
                    const float4 qx = *reinterpret_cast<const float4*>(qrow + 4*i);
                    a += qx.x * w[4*i] + qx.y * w[4*i+1] + qx.z * w[4*i+2] + qx.w * w[4*i+3];
                }
                qE[(size_t)(r0 + r) * (H_ * DKE_) + hj] = f2bf(a);
            }
        }
    } else if (blockIdx.x < 256) {
        const int r0 = (blockIdx.x - 128) * 8;          // global (b,m) row
        reinterpret_cast<float4*>(&Xs[0][0])[t] =
            reinterpret_cast<const float4*>(value + (size_t)r0 * D_)[t];
        __syncthreads();

        float acc[8] = {0,0,0,0,0,0,0,0};
        const float* wcol = Wv + (t >> 5) * (D_ * O_) + (t & 31);
        for (int k = 0; k < D_; k += 4) {
            const float w0 = wcol[(k+0) * O_];
            const float w1 = wcol[(k+1) * O_];
            const float w2 = wcol[(k+2) * O_];
            const float w3 = wcol[(k+3) * O_];
#pragma unroll
            for (int r = 0; r < 8; ++r) {
                const float4 x = *reinterpret_cast<const float4*>(&Xs[r][k]);
                acc[r] += x.x * w0 + x.y * w1 + x.z * w2 + x.w * w3;
            }
        }
        const int bb = r0 >> 9, m0 = r0 & 511;
        union { u32 u[4]; uint4 q; } pk;
        pk.u[0] = pk2bf(acc[0], acc[1]);
        pk.u[1] = pk2bf(acc[2], acc[3]);
        pk.u[2] = pk2bf(acc[4], acc[5]);
        pk.u[3] = pk2bf(acc[6], acc[7]);
        *reinterpret_cast<uint4*>(vvT + (size_t)bb * 256 * M_ + (size_t)t * M_ + m0) = pk.q;
    } else {
        // keyB: bf16 cast of key (2*512*128 floats), coalesced
        const int g = (blockIdx.x - 256) * 256 + t;     // 0..4095
        const float4* src = reinterpret_cast<const float4*>(key);
#pragma unroll
        for (int j = 0; j < 8; ++j) {
            const int i4 = g + j * 4096;                // float4 index
            const float4 x = src[i4];
            uint2 p;
            p.x = pk2bf(x.x, x.y);
            p.y = pk2bf(x.z, x.w);
            *reinterpret_cast<uint2*>(keyB + (size_t)i4 * 4) = p;
        }
    }
}

// ---------------------------------------------------------------------------
// k_attn: per (b,n). Logits via MFMA 16x16x32 bf16:
//   A = qE rows (bf16), B = cat(keyB, edge) per m-tile.
//   key frags: 4 direct bf16x8 loads (L2-hot).
//   edge: wave-private double-buffered global_load_lds DMA (fp32, 4 KB/tile,
//         chunk-transposed LDS layout -> bank-floor ds_read_b128), cvt->bf16.
// Then softmax, bf16 PV, projection. grid = 1024 x 256.
// ---------------------------------------------------------------------------
__global__ __launch_bounds__(256, 3) void k_attn(
    const u16* __restrict__ keyB, const float* __restrict__ edge,
    const u16* __restrict__ qE, const u16* __restrict__ vvT,
    const float* __restrict__ Wp, const float* __restrict__ bias,
    float* __restrict__ out)
{
    const int idx  = blockIdx.x;          // b*N + n
    const int b    = idx >> 9;
    const int t    = threadIdx.x;
    const int lane = t & 63;
    const int wv   = t >> 6;
    const int br   = lane & 15;           // B m-row in tile / A head-row
    const int q    = lane >> 4;           // k-quad

    __shared__ __attribute__((aligned(16))) unsigned char Ebuf[4][2][4096]; // 32 KB
    __shared__ __attribute__((aligned(16))) float attn_s[H_][MP_];          // 16.5 KB
    __shared__ float mh_s[H_ * O_];
    __shared__ float part_s[2][OUT_];

    // ---- A fragments: lane holds qE[row=br][kk*32 + q*8 + 0..7], rows>=8 zero
    bf16x8 afr[6];
    if (br < 8) {
        const u16* ab = qE + (size_t)idx * (H_ * DKE_) + br * DKE_;
#pragma unroll
        for (int kk = 0; kk < 6; ++kk)
            afr[kk] = *reinterpret_cast<const bf16x8*>(ab + kk * 32 + q * 8);
    } else {
#pragma unroll
        for (int kk = 0; kk < 6; ++kk) afr[kk] = bf16x8{0,0,0,0,0,0,0,0};
    }

    const u16*   kb  = keyB + (size_t)b * M_ * D_;
    const float* eb  = edge + (size_t)idx * M_ * DE_;
    // per-lane DMA source base: row = lane&15, chunk-quad = lane>>4
    const float* ebl = eb + (size_t)(lane & 15) * DE_ + (lane >> 4) * 4;

    // prologue: DMA edge tile (wv) into buf 0  [queue: dma 4]
    {
        const float* s = ebl + (size_t)(wv * 16) * DE_;
        char* d = (char*)&Ebuf[wv][0][0];
#pragma unroll
        for (int i = 0; i < 4; ++i) dma16(s + i * 16, d + i * 1024);
    }

    int buf = 0;
#pragma unroll 1
    for (int it = 0; it < 8; ++it) {
        const int tl = it * 4 + wv;
        const int m  = tl * 16 + br;
        // key fragments first (so vmcnt(4) later retires them + older DMA,
        // leaving the next-tile DMA in flight)
        const u16* kr = kb + (size_t)m * D_ + q * 8;
        const bf16x8 kf0 = *reinterpret_cast<const bf16x8*>(kr);
        const bf16x8 kf1 = *reinterpret_cast<const bf16x8*>(kr + 32);
        const bf16x8 kf2 = *reinterpret_cast<const bf16x8*>(kr + 64);
        const bf16x8 kf3 = *reinterpret_cast<const bf16x8*>(kr + 96);
        MEMFENCE();
        // prefetch next edge tile into the other buffer
        if (it < 7) {
            const float* s = ebl + (size_t)((tl + 4) * 16) * DE_;
            char* d = (char*)&Ebuf[wv][buf ^ 1][0];
#pragma unroll
            for (int i = 0; i < 4; ++i) dma16(s + i * 16, d + i * 1024);
        }
        MEMFENCE();
        __builtin_amdgcn_s_waitcnt(0x0F74);   // vmcnt(4): key(t)+dma(t) done
        MEMFENCE();

        floatx4 acc = {0.f, 0.f, 0.f, 0.f};
        acc = __builtin_amdgcn_mfma_f32_16x16x32_bf16(afr[0], kf0, acc, 0, 0, 0);
        acc = __builtin_amdgcn_mfma_f32_16x16x32_bf16(afr[1], kf1, acc, 0, 0, 0);
        acc = __builtin_amdgcn_mfma_f32_16x16x32_bf16(afr[2], kf2, acc, 0, 0, 0);
        acc = __builtin_amdgcn_mfma_f32_16x16x32_bf16(afr[3], kf3, acc, 0, 0, 0);
        // edge fragments: LDS[chunk][row] layout; chunk = k4, row = m-row
        const char* ebase = (const char*)&Ebuf[wv][buf][0];
#pragma unroll
        for (int kk = 0; kk < 2; ++kk) {
            const float4 r0 = *reinterpret_cast<const float4*>(ebase + kk * 2048 + q * 512 + br * 16);
            const float4 r1 = *reinterpret_cast<const float4*>(ebase + kk * 2048 + q * 512 + 256 + br * 16);
            acc = __builtin_amdgcn_mfma_f32_16x16x32_bf16(afr[4 + kk], pack8(r0, r1), acc, 0, 0, 0);
        }
        if (q < 2) {
#pragma unroll
            for (int i = 0; i < 4; ++i)
                attn_s[q * 4 + i][tl * 16 + br] = acc[i];
        }
        buf ^= 1;
    }
    __syncthreads();

    // ---- softmax over m per head (32 lanes own one head row) ----
    {
        const int h = t >> 5, ml = t & 31;
        float mx = -3.4e38f;
#pragma unroll 2
        for (int j = 0; j < 16; ++j) mx = fmaxf(mx, attn_s[h][ml + 32 * j]);
#pragma unroll
        for (int mask = 16; mask >= 1; mask >>= 1) mx = fmaxf(mx, __shfl_xor(mx, mask, 64));
        float sum = 0.f;
#pragma unroll 2
        for (int j = 0; j < 16; ++j) {
            const int m = ml + 32 * j;
            const float p = __expf(attn_s[h][m] - mx);
            attn_s[h][m] = p;
            sum += p;
        }
#pragma unroll
        for (int mask = 16; mask >= 1; mask >>= 1) sum += __shfl_xor(sum, mask, 64);
        const float inv = 1.f / sum;
#pragma unroll 2
        for (int j = 0; j < 16; ++j) attn_s[h][ml + 32 * j] *= inv;
    }
    __syncthreads();

    // ---- mh[h][o]: thread=(h,o)=t streams vvT[b][t][*] (contiguous bf16) ----
    {
        const int hh = t >> 5;
        const u16* vrow = vvT + (size_t)b * 256 * M_ + (size_t)t * M_;
        float a0 = 0.f, a1 = 0.f;
        for (int m0 = 0; m0 < M_; m0 += 8) {
            const bf16x8 v8 = *reinterpret_cast<const bf16x8*>(vrow + m0);
            const float4 w0 = *reinterpret_cast<const float4*>(&attn_s[hh][m0]);
            const float4 w1 = *reinterpret_cast<const float4*>(&attn_s[hh][m0 + 4]);
            a0 += w0.x * bf2f((u16)v8[0]) + w0.y * bf2f((u16)v8[1])
                + w0.z * bf2f((u16)v8[2]) + w0.w * bf2f((u16)v8[3]);
            a1 += w1.x * bf2f((u16)v8[4]) + w1.y * bf2f((u16)v8[5])
                + w1.z * bf2f((u16)v8[6]) + w1.w * bf2f((u16)v8[7]);
        }
        mh_s[t] = a0 + a1;
    }
    __syncthreads();

    // ---- out[c] = bias[c] + sum_j mh[j] * Wp[j*128 + c] ----
    {
        const int half = t >> 7;
        const int c = t & 127;
        float acc = 0.f;
        const int j0 = half * 128;
#pragma unroll 8
        for (int jj = 0; jj < 128; ++jj)
            acc += mh_s[j0 + jj] * Wp[(size_t)(j0 + jj) * OUT_ + c];
        part_s[half][c] = acc;
    }
    __syncthreads();
    if (t < OUT_)
        out[(size_t)idx * OUT_ + t] = part_s[0][t] + part_s[1][t] + bias[t];
}

// ---------------------------------------------------------------------------
extern "C" void kernel_launch(void* const* d_in, const int* in_sizes, int n_in,
                              void* d_out, int out_size, void* d_ws, size_t ws_size,
                              hipStream_t stream)
{
    const float* query = (const float*)d_in[0];   // [B,N,128]
    const float* key   = (const float*)d_in[1];   // [B,M,128]
    const float* value = (const float*)d_in[2];   // [B,M,128]
    const float* edge  = (const float*)d_in[3];   // [B,N,M,64]
    const float* Wq    = (const float*)d_in[4];   // [8,128,32]
    const float* Wk    = (const float*)d_in[5];   // [8,192,32]
    const float* Wv    = (const float*)d_in[6];   // [8,128,32]
    const float* Wp    = (const float*)d_in[7];   // [8,32,128]
    const float* bias  = (const float*)d_in[8];   // [128]
    float* out = (float*)d_out;                   // [B,N,128] fp32

    u16* ws    = (u16*)d_ws;
    u16* qE_ws = ws;                              // 1024*1536       = 1,572,864 u16
    u16* vT_ws = ws + 1572864;                    // 2*256*512       =   262,144 u16
    u16* kB_ws = ws + 1835008;                    // 2*512*128       =   131,072 u16  (total 3.93 MB)

    k_proj<<<272,  256, 0, stream>>>(query, Wq, Wk, value, Wv, key, qE_ws, vT_ws, kB_ws);
    k_attn<<<1024, 256, 0, stream>>>(kB_ws, edge, qE_ws, vT_ws, Wp, bias, out);
}